// Round 1
// baseline (1061.448 us; speedup 1.0000x reference)
//
#include <hip/hip_runtime.h>

// Problem constants
#define B_DIM 16
#define C_DIM 256
#define H_DIM 32
#define W_DIM 32
#define HW 1024                 // H*W
#define N_TOT 16384             // B*H*W
#define K_DIM 8192
#define ZQ_SIZE 4194304         // B*C*H*W
#define LOSS_OFF ZQ_SIZE
#define IDX_OFF (ZQ_SIZE + 1)

// Workspace layout (units of 4 bytes)
#define WS_ENORM 0              // 8192 floats
#define WS_PVAL  8192           // 16384*4 floats
#define WS_PIDX  73728          // 16384*4 ints
#define WS_FIDX  139264         // 16384 ints
#define WS_LPART 155648         // 2048 floats
// total ~631 KB of d_ws used

// ---------------- kernel 1: codebook row norms ----------------
__global__ __launch_bounds__(256) void k_enorm(const float* __restrict__ e,
                                               float* __restrict__ enorm) {
    int gwave = (blockIdx.x * 256 + threadIdx.x) >> 6;   // one wave per k row
    int lane = threadIdx.x & 63;
    const float4 v = *reinterpret_cast<const float4*>(e + (size_t)gwave * C_DIM + lane * 4);
    float s = v.x * v.x + v.y * v.y + v.z * v.z + v.w * v.w;
    #pragma unroll
    for (int off = 32; off; off >>= 1) s += __shfl_xor(s, off, 64);
    if (lane == 0) enorm[gwave] = s;
}

// ---------------- kernel 2: fused distance GEMM + per-row argmin ----------------
#define BM 64
#define BN 64
#define CT 64
#define PITCH 68                // 64 + 4 pad: keeps float4 alignment, bank stride 4
#define NSPLIT 4
#define KSPLIT (K_DIM / NSPLIT) // 2048

__global__ __launch_bounds__(256, 4) void k_dist(const float* __restrict__ z,
                                                 const float* __restrict__ e,
                                                 const float* __restrict__ enorm,
                                                 float* __restrict__ pval,
                                                 int* __restrict__ pidx) {
    __shared__ float smem[2 * CT * PITCH];
    float* zt = smem;                 // [CT][PITCH]  c-major, columns = n_local
    float* et = smem + CT * PITCH;    // [CT][PITCH]  c-major, columns = k_local

    const int tid = threadIdx.x;
    const int tx = tid & 15;          // k-quad
    const int ty = tid >> 4;          // n-quad
    const int ntile = blockIdx.x >> 2;      // 0..255
    const int ks = blockIdx.x & 3;          // K split
    const int n0 = ntile * BM;
    const int b = n0 >> 10;
    const int hw0 = n0 & 1023;
    const float* zb = z + (size_t)b * C_DIM * HW + hw0;  // zf[n0+j][c] = zb[c*HW + j]

    float minv[4] = {3.4e38f, 3.4e38f, 3.4e38f, 3.4e38f};
    int   mini[4] = {0, 0, 0, 0};
    float acc[4][4];

    const int k_begin = ks * KSPLIT;
    const int k_end = k_begin + KSPLIT;

    for (int kt = k_begin; kt < k_end; kt += BN) {
        #pragma unroll
        for (int u = 0; u < 4; ++u)
            #pragma unroll
            for (int v = 0; v < 4; ++v) acc[u][v] = 0.0f;

        for (int ct = 0; ct < C_DIM; ct += CT) {
            // stage z tile [CT c][64 n] and e tile transposed [CT c][64 k]
            #pragma unroll
            for (int i = tid; i < CT * 16; i += 256) {
                int row = i >> 4;     // c_local for z, k_local for e
                int q = i & 15;
                float4 zv = *reinterpret_cast<const float4*>(zb + (size_t)(ct + row) * HW + q * 4);
                *reinterpret_cast<float4*>(&zt[row * PITCH + q * 4]) = zv;
                float4 ev = *reinterpret_cast<const float4*>(
                    e + (size_t)(kt + row) * C_DIM + ct + q * 4);
                et[(q * 4 + 0) * PITCH + row] = ev.x;
                et[(q * 4 + 1) * PITCH + row] = ev.y;
                et[(q * 4 + 2) * PITCH + row] = ev.z;
                et[(q * 4 + 3) * PITCH + row] = ev.w;
            }
            __syncthreads();
            #pragma unroll 16
            for (int c = 0; c < CT; ++c) {
                const float4 av = *reinterpret_cast<const float4*>(&zt[c * PITCH + (ty << 2)]);
                const float4 bv = *reinterpret_cast<const float4*>(&et[c * PITCH + (tx << 2)]);
                acc[0][0] = fmaf(av.x, bv.x, acc[0][0]);
                acc[0][1] = fmaf(av.x, bv.y, acc[0][1]);
                acc[0][2] = fmaf(av.x, bv.z, acc[0][2]);
                acc[0][3] = fmaf(av.x, bv.w, acc[0][3]);
                acc[1][0] = fmaf(av.y, bv.x, acc[1][0]);
                acc[1][1] = fmaf(av.y, bv.y, acc[1][1]);
                acc[1][2] = fmaf(av.y, bv.z, acc[1][2]);
                acc[1][3] = fmaf(av.y, bv.w, acc[1][3]);
                acc[2][0] = fmaf(av.z, bv.x, acc[2][0]);
                acc[2][1] = fmaf(av.z, bv.y, acc[2][1]);
                acc[2][2] = fmaf(av.z, bv.z, acc[2][2]);
                acc[2][3] = fmaf(av.z, bv.w, acc[2][3]);
                acc[3][0] = fmaf(av.w, bv.x, acc[3][0]);
                acc[3][1] = fmaf(av.w, bv.y, acc[3][1]);
                acc[3][2] = fmaf(av.w, bv.z, acc[3][2]);
                acc[3][3] = fmaf(av.w, bv.w, acc[3][3]);
            }
            __syncthreads();
        }
        // distance = ||e||^2 - 2*dot (row-constant ||z||^2 omitted); running argmin
        const float4 en = *reinterpret_cast<const float4*>(enorm + kt + (tx << 2));
        const float env[4] = {en.x, en.y, en.z, en.w};
        #pragma unroll
        for (int v = 0; v < 4; ++v) {
            int k = kt + (tx << 2) + v;
            #pragma unroll
            for (int u = 0; u < 4; ++u) {
                float d = env[v] - 2.0f * acc[u][v];
                if (d < minv[u]) { minv[u] = d; mini[u] = k; }  // strict <: first-occurrence
            }
        }
    }

    // cross-tx reduction via LDS (reuse smem; all compute barriers passed)
    float* rv = smem;              // [64][16]
    int* ri = (int*)(smem + 1024); // [64][16]
    #pragma unroll
    for (int u = 0; u < 4; ++u) {
        rv[(ty * 4 + u) * 16 + tx] = minv[u];
        ri[(ty * 4 + u) * 16 + tx] = mini[u];
    }
    __syncthreads();
    if (tid < 64) {
        float bv = rv[tid * 16];
        int bi = ri[tid * 16];
        #pragma unroll
        for (int t = 1; t < 16; ++t) {
            float v = rv[tid * 16 + t];
            int iv = ri[tid * 16 + t];
            if (v < bv || (v == bv && iv < bi)) { bv = v; bi = iv; }
        }
        pval[(size_t)(n0 + tid) * NSPLIT + ks] = bv;
        pidx[(size_t)(n0 + tid) * NSPLIT + ks] = bi;
    }
}

// ---------------- kernel 3: merge K-splits, emit final indices ----------------
__global__ __launch_bounds__(256) void k_fin(const float* __restrict__ pval,
                                             const int* __restrict__ pidx,
                                             int* __restrict__ fidx,
                                             float* __restrict__ out_idx) {
    int n = blockIdx.x * 256 + threadIdx.x;
    if (n >= N_TOT) return;
    float bv = pval[n * 4];
    int bi = pidx[n * 4];
    #pragma unroll
    for (int s = 1; s < 4; ++s) {
        float v = pval[n * 4 + s];
        int iv = pidx[n * 4 + s];
        if (v < bv || (v == bv && iv < bi)) { bv = v; bi = iv; }
    }
    fidx[n] = bi;
    out_idx[n] = (float)bi;
}

// ---------------- kernel 4: gather z_q + per-block loss partials ----------------
#define GBLOCKS 2048
__global__ __launch_bounds__(256) void k_gather(const float* __restrict__ z,
                                                const float* __restrict__ e,
                                                const int* __restrict__ fidx,
                                                float* __restrict__ zq,
                                                float* __restrict__ lpart) {
    float s = 0.0f;
    for (int i = blockIdx.x * 256 + threadIdx.x; i < ZQ_SIZE; i += GBLOCKS * 256) {
        int bb = i >> 18;           // / (C*HW)
        int c = (i >> 10) & 255;
        int hw = i & 1023;
        int n = (bb << 10) | hw;
        float q = e[(size_t)fidx[n] * C_DIM + c];
        float zv = z[i];
        zq[i] = q;
        float d = q - zv;
        s = fmaf(d, d, s);
    }
    #pragma unroll
    for (int off = 32; off; off >>= 1) s += __shfl_xor(s, off, 64);
    __shared__ float wsum[4];
    int lane = threadIdx.x & 63, w = threadIdx.x >> 6;
    if (lane == 0) wsum[w] = s;
    __syncthreads();
    if (threadIdx.x == 0) lpart[blockIdx.x] = wsum[0] + wsum[1] + wsum[2] + wsum[3];
}

// ---------------- kernel 5: final loss reduce ----------------
__global__ __launch_bounds__(256) void k_loss(const float* __restrict__ lpart,
                                              float* __restrict__ out_loss) {
    float s = 0.0f;
    for (int i = threadIdx.x; i < GBLOCKS; i += 256) s += lpart[i];
    #pragma unroll
    for (int off = 32; off; off >>= 1) s += __shfl_xor(s, off, 64);
    __shared__ float wsum[4];
    int lane = threadIdx.x & 63, w = threadIdx.x >> 6;
    if (lane == 0) wsum[w] = s;
    __syncthreads();
    if (threadIdx.x == 0) {
        float total = wsum[0] + wsum[1] + wsum[2] + wsum[3];
        // loss = BETA*mean + mean = 1.25 * mean((z_q - z)^2)
        out_loss[0] = total * (1.25f / (float)ZQ_SIZE);
    }
}

extern "C" void kernel_launch(void* const* d_in, const int* in_sizes, int n_in,
                              void* d_out, int out_size, void* d_ws, size_t ws_size,
                              hipStream_t stream) {
    const float* z = (const float*)d_in[0];
    const float* e = (const float*)d_in[1];
    float* out = (float*)d_out;
    float* ws = (float*)d_ws;

    float* enorm = ws + WS_ENORM;
    float* pval = ws + WS_PVAL;
    int* pidx = (int*)(ws + WS_PIDX);
    int* fidx = (int*)(ws + WS_FIDX);
    float* lpart = ws + WS_LPART;

    k_enorm<<<dim3(K_DIM / 4), dim3(256), 0, stream>>>(e, enorm);
    k_dist<<<dim3(256 * NSPLIT), dim3(256), 0, stream>>>(z, e, enorm, pval, pidx);
    k_fin<<<dim3(N_TOT / 256), dim3(256), 0, stream>>>(pval, pidx, fidx, out + IDX_OFF);
    k_gather<<<dim3(GBLOCKS), dim3(256), 0, stream>>>(z, e, fidx, out, lpart);
    k_loss<<<dim3(1), dim3(256), 0, stream>>>(lpart, out + LOSS_OFF);
}

// Round 3
// 387.893 us; speedup vs baseline: 2.7364x; 2.7364x over previous
//
#include <hip/hip_runtime.h>

typedef unsigned int u32;
typedef unsigned long long u64;

#define C_DIM 256
#define HW 1024
#define N_TOT 16384
#define K_DIM 8192
#define ZQ_SIZE 4194304
#define LOSS_OFF ZQ_SIZE
#define IDX_OFF (ZQ_SIZE + 1)

#define KRANGE 2048
#define NKT 16
#define MARGIN 2.0f
#define CAP 524288u

// workspace offsets (floats)
#define WS_ENORM 0          // 8192
#define WS_CNT 8192         // 1 u32
#define WS_ROWMIN 16384     // 16384
#define WS_PACKED 32768     // 16384 u64 = 32768 f
#define WS_FIDX 65536       // 16384
#define WS_ROWMIN4 81920    // 65536
#define WS_LPART 147456     // 2048
#define WS_LIST 163840      // CAP uint2 = 1048576 f
#define WS_ZT32 1212416     // 4194304
#define WS_ZTB16 5406720    // 2097152
#define WS_EB16 7503872     // 1048576 -> ends 8552448 f = 34.2 MB

typedef __attribute__((ext_vector_type(4))) float f32x4;
typedef __attribute__((ext_vector_type(8))) __bf16 bf16x8;
typedef __attribute__((ext_vector_type(8))) unsigned short u16x8;

__device__ __forceinline__ void gld_lds16(const void* g, void* l) {
    __builtin_amdgcn_global_load_lds(
        (const __attribute__((address_space(1))) u32*)g,
        (__attribute__((address_space(3))) u32*)l, 16, 0, 0);
}

__device__ __forceinline__ unsigned short f2bf(float f) {
    u32 u = __float_as_uint(f);
    u32 r = (u + 0x7FFFu + ((u >> 16) & 1u)) >> 16;   // RNE
    return (unsigned short)r;
}

// ---------------- prep e: bf16 codebook + fp32 row norms ----------------
__global__ __launch_bounds__(256) void k_prep_e(const float* __restrict__ e,
                                                unsigned short* __restrict__ eb,
                                                float* __restrict__ enorm) {
    int w = threadIdx.x >> 6, l = threadIdx.x & 63;
    int row = blockIdx.x * 4 + w;
    const float4 v = *reinterpret_cast<const float4*>(e + (size_t)row * C_DIM + l * 4);
    float s = v.x * v.x + v.y * v.y + v.z * v.z + v.w * v.w;
    #pragma unroll
    for (int off = 32; off; off >>= 1) s += __shfl_xor(s, off, 64);
    if (l == 0) enorm[row] = s;
    ushort4 h;
    h.x = f2bf(v.x); h.y = f2bf(v.y); h.z = f2bf(v.z); h.w = f2bf(v.w);
    *reinterpret_cast<ushort4*>(eb + (size_t)row * C_DIM + l * 4) = h;
}

// ---------------- prep z: transpose to [n][c], fp32 + bf16 ----------------
__global__ __launch_bounds__(256) void k_prep_z(const float* __restrict__ z,
                                                float* __restrict__ zt32,
                                                unsigned short* __restrict__ ztb) {
    int bid = blockIdx.x;
    int b = bid >> 7;
    int hwt = (bid >> 3) & 15;
    int ct = bid & 7;
    int t = threadIdx.x;
    __shared__ float tile[32][65];
    #pragma unroll
    for (int p = 0; p < 8; ++p) {
        int cl = p * 4 + (t >> 6), hl = t & 63;
        tile[cl][hl] = z[((size_t)b << 18) + ((size_t)(ct * 32 + cl) << 10) + hwt * 64 + hl];
    }
    __syncthreads();
    int hl = t & 63, cg = t >> 6;
    int n = (b << 10) + hwt * 64 + hl;
    float v[8];
    #pragma unroll
    for (int j = 0; j < 8; ++j) v[j] = tile[cg * 8 + j][hl];
    size_t base = (size_t)n * C_DIM + ct * 32 + cg * 8;
    *reinterpret_cast<float4*>(zt32 + base) = make_float4(v[0], v[1], v[2], v[3]);
    *reinterpret_cast<float4*>(zt32 + base + 4) = make_float4(v[4], v[5], v[6], v[7]);
    u16x8 h;
    #pragma unroll
    for (int j = 0; j < 8; ++j) h[j] = f2bf(v[j]);
    *reinterpret_cast<u16x8*>(ztb + base) = h;
}

// ---------------- MFMA screen: PHASE 1 = per-(row,split) min; PHASE 2 = flag ----------------
template<int PHASE>
__global__ __launch_bounds__(256, 2) void k_screen(const unsigned short* __restrict__ zt,
                                                   const unsigned short* __restrict__ et,
                                                   const float* __restrict__ enorm,
                                                   const float* __restrict__ rowmin_g,
                                                   float* __restrict__ rowmin4,
                                                   u32* __restrict__ cnt,
                                                   uint2* __restrict__ list) {
    __shared__ __align__(16) char lds[81920];   // A 65536 + B 16384
    char* Ab = lds;
    char* Bb = lds + 65536;

    int hw_id = blockIdx.x;
    int logical = (hw_id & 7) * 64 + (hw_id >> 3);   // bijective, XCD-grouped
    const int ks = logical >> 7;
    const int rowtile = logical & 127;
    const int n0 = rowtile * 128;
    const int kbase = ks * KRANGE;

    const int tid = threadIdx.x;
    const int l = tid & 63, w = tid >> 6;
    const int wr = w >> 1, wc = w & 1;

    // stage A once: 128 rows x 256 c bf16 (inverse-swizzled source, linear dest)
    #pragma unroll
    for (int j = 0; j < 16; ++j) {
        int Y = (w * 16 + j) * 1024 + l * 16;
        int row = Y >> 9;
        int slot = (Y >> 4) & 31;
        const char* src = (const char*)zt + (((size_t)(n0 + row)) << 9) + ((slot ^ (row & 7)) << 4);
        gld_lds16(src, Ab + (w * 16 + j) * 1024);
    }

    const char* bsrc0[4];
    #pragma unroll
    for (int j = 0; j < 4; ++j) {
        int Y = (w * 4 + j) * 1024 + l * 16;
        int row = Y >> 7;
        int slot = (Y >> 4) & 7;
        bsrc0[j] = (const char*)et + ((size_t)row << 9) + ((slot ^ (row & 7)) << 4);
    }

    float minv[16];
    float rmv[16];
    #pragma unroll
    for (int s = 0; s < 16; ++s) {
        if constexpr (PHASE == 1) {
            minv[s] = 3.4e38f;
        } else {
            int row_local = wr * 64 + (s >> 2) * 16 + ((l >> 4) << 2) + (s & 3);
            rmv[s] = rowmin_g[n0 + row_local] + MARGIN;
        }
    }

    for (int it = 0; it < NKT; ++it) {
        const size_t koff = ((size_t)(kbase + it * 128)) << 9;   // bytes
        f32x4 acc[4][4];
        #pragma unroll
        for (int a = 0; a < 4; ++a)
            #pragma unroll
            for (int b = 0; b < 4; ++b) acc[a][b] = (f32x4){0.f, 0.f, 0.f, 0.f};

        for (int ct = 0; ct < 4; ++ct) {
            #pragma unroll
            for (int j = 0; j < 4; ++j)
                gld_lds16(bsrc0[j] + koff + (ct << 7), Bb + (w * 4 + j) * 1024);
            __syncthreads();
            #pragma unroll
            for (int sub = 0; sub < 2; ++sub) {
                bf16x8 af[4], bfr[4];
                #pragma unroll
                for (int mf = 0; mf < 4; ++mf) {
                    int row = wr * 64 + mf * 16 + (l & 15);
                    int slot = ct * 8 + sub * 4 + (l >> 4);
                    af[mf] = *reinterpret_cast<const bf16x8*>(Ab + row * 512 + ((slot ^ (row & 7)) << 4));
                }
                #pragma unroll
                for (int kf = 0; kf < 4; ++kf) {
                    int row = wc * 64 + kf * 16 + (l & 15);
                    int slot = sub * 4 + (l >> 4);
                    bfr[kf] = *reinterpret_cast<const bf16x8*>(Bb + row * 128 + ((slot ^ (row & 7)) << 4));
                }
                #pragma unroll
                for (int mf = 0; mf < 4; ++mf)
                    #pragma unroll
                    for (int kf = 0; kf < 4; ++kf)
                        acc[mf][kf] = __builtin_amdgcn_mfma_f32_16x16x32_bf16(
                            af[mf], bfr[kf], acc[mf][kf], 0, 0, 0);
            }
            __syncthreads();
        }

        #pragma unroll
        for (int kf = 0; kf < 4; ++kf) {
            int kcol = kbase + it * 128 + wc * 64 + kf * 16 + (l & 15);
            float en = enorm[kcol];
            #pragma unroll
            for (int mf = 0; mf < 4; ++mf) {
                #pragma unroll
                for (int r = 0; r < 4; ++r) {
                    float d = fmaf(-2.0f, acc[mf][kf][r], en);
                    int slot = mf * 4 + r;
                    if constexpr (PHASE == 1) {
                        minv[slot] = fminf(minv[slot], d);
                    } else {
                        if (d <= rmv[slot]) {
                            int n = n0 + wr * 64 + mf * 16 + ((l >> 4) << 2) + r;
                            u32 pos = atomicAdd(cnt, 1u);
                            if (pos < CAP) list[pos] = make_uint2((u32)n, (u32)kcol);
                        }
                    }
                }
            }
        }
    }

    if constexpr (PHASE == 1) {
        // butterfly min over the 16-lane group (same row set, different k columns)
        #pragma unroll
        for (int m = 1; m <= 8; m <<= 1)
            #pragma unroll
            for (int s = 0; s < 16; ++s)
                minv[s] = fminf(minv[s], __shfl_xor(minv[s], m, 64));
        // merge the two wave-columns via LDS (all compute barriers passed)
        float* LDSmin = (float*)lds;   // [128][2]
        if ((l & 15) == 0) {
            #pragma unroll
            for (int s = 0; s < 16; ++s) {
                int row_local = wr * 64 + (s >> 2) * 16 + ((l >> 4) << 2) + (s & 3);
                LDSmin[row_local * 2 + wc] = minv[s];
            }
        }
        __syncthreads();
        if (tid < 128)
            rowmin4[(size_t)(n0 + tid) * 4 + ks] = fminf(LDSmin[tid * 2], LDSmin[tid * 2 + 1]);
    }
}

// ---------------- merge 4 k-splits to per-row global bf16 min ----------------
__global__ __launch_bounds__(256) void k_merge(const float* __restrict__ rowmin4,
                                               float* __restrict__ rowmin) {
    int n = blockIdx.x * 256 + threadIdx.x;
    if (n >= N_TOT) return;
    float m = rowmin4[n * 4];
    #pragma unroll
    for (int s = 1; s < 4; ++s) m = fminf(m, rowmin4[n * 4 + s]);
    rowmin[n] = m;
}

// ---------------- exact fp32 recheck of candidates ----------------
__global__ __launch_bounds__(256) void k_exact(const float* __restrict__ zt32,
                                               const float* __restrict__ e,
                                               const float* __restrict__ enorm,
                                               const u32* __restrict__ cnt,
                                               const uint2* __restrict__ list,
                                               u64* __restrict__ packed) {
    const int nw = gridDim.x * 4;
    const int wid = blockIdx.x * 4 + (threadIdx.x >> 6);
    const int l = threadIdx.x & 63;
    u32 total = *cnt;
    if (total > CAP) total = CAP;
    for (u32 i = wid; i < total; i += nw) {
        uint2 c = list[i];
        const float4 zv = *reinterpret_cast<const float4*>(zt32 + (size_t)c.x * C_DIM + l * 4);
        const float4 ev = *reinterpret_cast<const float4*>(e + (size_t)c.y * C_DIM + l * 4);
        float s = zv.x * ev.x + zv.y * ev.y + zv.z * ev.z + zv.w * ev.w;
        #pragma unroll
        for (int off = 32; off; off >>= 1) s += __shfl_xor(s, off, 64);
        if (l == 0) {
            float d = fmaf(-2.0f, s, enorm[c.y]);
            u32 ub = __float_as_uint(d);
            ub = (ub & 0x80000000u) ? ~ub : (ub | 0x80000000u);
            u64 key = ((u64)ub << 32) | (u64)c.y;
            atomicMin(packed + c.x, key);
        }
    }
}

// ---------------- finalize indices ----------------
__global__ __launch_bounds__(256) void k_fin(const u64* __restrict__ packed,
                                             int* __restrict__ fidx,
                                             float* __restrict__ out_idx) {
    int n = blockIdx.x * 256 + threadIdx.x;
    if (n >= N_TOT) return;
    int k = (int)(u32)(packed[n] & 0xFFFFFFFFull);
    fidx[n] = k;
    out_idx[n] = (float)k;
}

// ---------------- gather z_q + loss partials ----------------
#define GBLOCKS 2048
__global__ __launch_bounds__(256) void k_gather(const float* __restrict__ z,
                                                const float* __restrict__ e,
                                                const int* __restrict__ fidx,
                                                float* __restrict__ zq,
                                                float* __restrict__ lpart) {
    float s = 0.0f;
    for (int i = blockIdx.x * 256 + threadIdx.x; i < ZQ_SIZE; i += GBLOCKS * 256) {
        int bb = i >> 18;
        int c = (i >> 10) & 255;
        int hw = i & 1023;
        int n = (bb << 10) | hw;
        float q = e[(size_t)fidx[n] * C_DIM + c];
        float zv = z[i];
        zq[i] = q;
        float d = q - zv;
        s = fmaf(d, d, s);
    }
    #pragma unroll
    for (int off = 32; off; off >>= 1) s += __shfl_xor(s, off, 64);
    __shared__ float wsum[4];
    int lane = threadIdx.x & 63, w = threadIdx.x >> 6;
    if (lane == 0) wsum[w] = s;
    __syncthreads();
    if (threadIdx.x == 0) lpart[blockIdx.x] = wsum[0] + wsum[1] + wsum[2] + wsum[3];
}

__global__ __launch_bounds__(256) void k_loss(const float* __restrict__ lpart,
                                              float* __restrict__ out_loss) {
    float s = 0.0f;
    for (int i = threadIdx.x; i < GBLOCKS; i += 256) s += lpart[i];
    #pragma unroll
    for (int off = 32; off; off >>= 1) s += __shfl_xor(s, off, 64);
    __shared__ float wsum[4];
    int lane = threadIdx.x & 63, w = threadIdx.x >> 6;
    if (lane == 0) wsum[w] = s;
    __syncthreads();
    if (threadIdx.x == 0)
        out_loss[0] = (wsum[0] + wsum[1] + wsum[2] + wsum[3]) * (1.25f / (float)ZQ_SIZE);
}

extern "C" void kernel_launch(void* const* d_in, const int* in_sizes, int n_in,
                              void* d_out, int out_size, void* d_ws, size_t ws_size,
                              hipStream_t stream) {
    const float* z = (const float*)d_in[0];
    const float* e = (const float*)d_in[1];
    float* out = (float*)d_out;
    float* ws = (float*)d_ws;

    float* enorm = ws + WS_ENORM;
    u32* cnt = (u32*)(ws + WS_CNT);
    float* rowmin = ws + WS_ROWMIN;
    u64* packed = (u64*)(ws + WS_PACKED);
    int* fidx = (int*)(ws + WS_FIDX);
    float* rowmin4 = ws + WS_ROWMIN4;
    float* lpart = ws + WS_LPART;
    uint2* list = (uint2*)(ws + WS_LIST);
    float* zt32 = ws + WS_ZT32;
    unsigned short* ztb = (unsigned short*)(ws + WS_ZTB16);
    unsigned short* eb = (unsigned short*)(ws + WS_EB16);

    hipMemsetAsync(cnt, 0, sizeof(u32), stream);
    hipMemsetAsync(packed, 0xFF, (size_t)N_TOT * sizeof(u64), stream);

    k_prep_e<<<dim3(K_DIM / 4), dim3(256), 0, stream>>>(e, eb, enorm);
    k_prep_z<<<dim3(2048), dim3(256), 0, stream>>>(z, zt32, ztb);
    k_screen<1><<<dim3(512), dim3(256), 0, stream>>>(ztb, eb, enorm, rowmin, rowmin4, cnt, list);
    k_merge<<<dim3(64), dim3(256), 0, stream>>>(rowmin4, rowmin);
    k_screen<2><<<dim3(512), dim3(256), 0, stream>>>(ztb, eb, enorm, rowmin, rowmin4, cnt, list);
    k_exact<<<dim3(512), dim3(256), 0, stream>>>(zt32, e, enorm, cnt, list, packed);
    k_fin<<<dim3(64), dim3(256), 0, stream>>>(packed, fidx, out + IDX_OFF);
    k_gather<<<dim3(GBLOCKS), dim3(256), 0, stream>>>(z, e, fidx, out, lpart);
    k_loss<<<dim3(1), dim3(256), 0, stream>>>(lpart, out + LOSS_OFF);
}

// Round 5
// 194.192 us; speedup vs baseline: 5.4660x; 1.9975x over previous
//
#include <hip/hip_runtime.h>

typedef unsigned int u32;
typedef unsigned long long u64;

#define C_DIM 256
#define HW 1024
#define N_TOT 16384
#define K_DIM 8192
#define ZQ_SIZE 4194304
#define LOSS_OFF ZQ_SIZE
#define IDX_OFF (ZQ_SIZE + 1)

#define KRANGE 2048
#define MARGIN 2.0f
#define CAP 524288u
#define LCAP 8192u

// workspace offsets (floats)
#define WS_ENORM 0          // 8192 (stores ||e||^2 + 1024)
#define WS_CNT 8192         // 1 u32
#define WS_PACKED 16384     // 16384 u64 = 32768 f
#define WS_FIDX 49152       // 16384
#define WS_LPART 65536      // 2048
#define WS_LIST 131072      // CAP uint2 = 1048576 f
#define WS_ZT32 1179648     // 4194304
#define WS_ZTB16 5373952    // 2097152
#define WS_EB16 7471104     // 1048576 -> ends 8519680 f = 34.1 MB

typedef __attribute__((ext_vector_type(4))) float f32x4;
typedef __attribute__((ext_vector_type(8))) __bf16 bf16x8;
typedef __attribute__((ext_vector_type(8))) unsigned short u16x8;

__device__ __forceinline__ void gld_lds16(const void* g, void* l) {
    __builtin_amdgcn_global_load_lds(
        (const __attribute__((address_space(1))) u32*)g,
        (__attribute__((address_space(3))) u32*)l, 16, 0, 0);
}

__device__ __forceinline__ unsigned short f2bf(float f) {
    u32 u = __float_as_uint(f);
    u32 r = (u + 0x7FFFu + ((u >> 16) & 1u)) >> 16;   // RNE
    return (unsigned short)r;
}

// ---------------- prep e: bf16 codebook + (||e||^2 + 1024) ----------------
__global__ __launch_bounds__(256) void k_prep_e(const float* __restrict__ e,
                                                unsigned short* __restrict__ eb,
                                                float* __restrict__ enorm1) {
    int w = threadIdx.x >> 6, l = threadIdx.x & 63;
    int row = blockIdx.x * 4 + w;
    const float4 v = *reinterpret_cast<const float4*>(e + (size_t)row * C_DIM + l * 4);
    float s = v.x * v.x + v.y * v.y + v.z * v.z + v.w * v.w;
    #pragma unroll
    for (int off = 32; off; off >>= 1) s += __shfl_xor(s, off, 64);
    if (l == 0) enorm1[row] = s + 1024.0f;
    ushort4 h;
    h.x = f2bf(v.x); h.y = f2bf(v.y); h.z = f2bf(v.z); h.w = f2bf(v.w);
    *reinterpret_cast<ushort4*>(eb + (size_t)row * C_DIM + l * 4) = h;
}

// ---------------- prep z: transpose to [n][c], fp32 + bf16 ----------------
__global__ __launch_bounds__(256) void k_prep_z(const float* __restrict__ z,
                                                float* __restrict__ zt32,
                                                unsigned short* __restrict__ ztb) {
    int bid = blockIdx.x;
    int b = bid >> 7;
    int hwt = (bid >> 3) & 15;
    int ct = bid & 7;
    int t = threadIdx.x;
    __shared__ float tile[32][65];
    #pragma unroll
    for (int p = 0; p < 8; ++p) {
        int cl = p * 4 + (t >> 6), hl = t & 63;
        tile[cl][hl] = z[((size_t)b << 18) + ((size_t)(ct * 32 + cl) << 10) + hwt * 64 + hl];
    }
    __syncthreads();
    int hl = t & 63, cg = t >> 6;
    int n = (b << 10) + hwt * 64 + hl;
    float v[8];
    #pragma unroll
    for (int j = 0; j < 8; ++j) v[j] = tile[cg * 8 + j][hl];
    size_t base = (size_t)n * C_DIM + ct * 32 + cg * 8;
    *reinterpret_cast<float4*>(zt32 + base) = make_float4(v[0], v[1], v[2], v[3]);
    *reinterpret_cast<float4*>(zt32 + base + 4) = make_float4(v[4], v[5], v[6], v[7]);
    u16x8 h;
    #pragma unroll
    for (int j = 0; j < 8; ++j) h[j] = f2bf(v[j]);
    *reinterpret_cast<u16x8*>(ztb + base) = h;
}

// ---------------- single-pass MFMA screen: packed (d,k) top-2 + candidate emission ----------------
__global__ __launch_bounds__(256, 2) void k_screen(const unsigned short* __restrict__ zt,
                                                   const unsigned short* __restrict__ et,
                                                   const float* __restrict__ enorm1,
                                                   u32* __restrict__ cnt,
                                                   uint2* __restrict__ list) {
    __shared__ __align__(16) char lds[81920];   // A 64KB + B 2x8KB
    char* Ab = lds;
    char* Bb = lds + 65536;

    int logical = (blockIdx.x & 7) * 64 + (blockIdx.x >> 3);   // bijective, XCD-grouped
    const int ks = logical >> 7;
    const int rowtile = logical & 127;
    const int n0 = rowtile * 128;
    const int kbase = ks * KRANGE;

    const int tid = threadIdx.x;
    const int l = tid & 63, w = tid >> 6;
    const int wr = w >> 1, wc = w & 1;
    const int ll = l & 15, lh = l >> 4;

    // ---- stage A once: 128 rows x 256 c bf16 (inverse-swizzled source, linear dest) ----
    #pragma unroll
    for (int j = 0; j < 16; ++j) {
        int Y = (w * 16 + j) * 1024 + l * 16;      // byte
        int row = Y >> 9;
        int slot = (Y >> 4) & 31;
        const char* src = (const char*)zt + (((size_t)(n0 + row)) << 9) + ((slot ^ (row & 7)) << 4);
        gld_lds16(src, Ab + (w * 16 + j) * 1024);
    }

    // ---- precompute B stage source pointers (per-lane), dest bases (uniform) ----
    const char* srcB[2];
    char* dstB[2];
    #pragma unroll
    for (int j = 0; j < 2; ++j) {
        int D = w * 128 + j * 64 + l;              // linear 16B-chunk in 8KB buffer
        int rB = D >> 2;
        int sB = (D & 3) ^ ((rB >> 1) & 3);
        srcB[j] = (const char*)et + ((size_t)(kbase + rB) << 9) + (sB << 4);
        dstB[j] = Bb + (w * 128 + j * 64) * 16;
    }

    // af addressing (row part constant)
    int aoff[4], rxA[4];
    #pragma unroll
    for (int mf = 0; mf < 4; ++mf) {
        int row = wr * 64 + mf * 16 + ll;
        aoff[mf] = row * 512;
        rxA[mf] = row & 7;
    }
    // bfr addressing (constant per kf: B chunk = row*4 + (lh ^ ((row>>1)&3)))
    int bfrOff[4];
    #pragma unroll
    for (int kf = 0; kf < 4; ++kf) {
        int row = wc * 64 + kf * 16 + ll;
        bfrOff[kf] = (row * 4 + (lh ^ ((row >> 1) & 3))) * 16;
    }

    f32x4 acc[4][4];
    #pragma unroll
    for (int a = 0; a < 4; ++a)
        #pragma unroll
        for (int b = 0; b < 4; ++b) acc[a][b] = (f32x4){0.f, 0.f, 0.f, 0.f};
    float m1[16], m2[16];
    #pragma unroll
    for (int s = 0; s < 16; ++s) { m1[s] = 3.4e38f; m2[s] = 3.4e38f; }

    // prologue: stage step 0 into buf0
    gld_lds16(srcB[0], dstB[0]);
    gld_lds16(srcB[1], dstB[1]);
    __syncthreads();

    for (int it = 0; it < 16; ++it) {
        // per-K-tile enorm prefetch (used at cs==7)
        float en[4];
        #pragma unroll
        for (int kf = 0; kf < 4; ++kf)
            en[kf] = enorm1[kbase + it * 128 + wc * 64 + kf * 16 + ll];

        #pragma unroll
        for (int cs = 0; cs < 8; ++cs) {
            const int p = cs & 1;
            // stage next step's B chunk into the other buffer (issue-early)
            if (it < 15 || cs < 7) {
                const size_t koff = (size_t)it * 65536 + ((cs == 7) ? 65536 : (cs + 1) * 64);
                gld_lds16(srcB[0] + koff, dstB[0] + (p ^ 1) * 8192);
                gld_lds16(srcB[1] + koff, dstB[1] + (p ^ 1) * 8192);
            }
            // fragments
            bf16x8 af[4], bfr[4];
            #pragma unroll
            for (int mf = 0; mf < 4; ++mf)
                af[mf] = *reinterpret_cast<const bf16x8*>(
                    Ab + aoff[mf] + (((cs * 4 + lh) ^ rxA[mf]) << 4));
            #pragma unroll
            for (int kf = 0; kf < 4; ++kf)
                bfr[kf] = *reinterpret_cast<const bf16x8*>(Bb + p * 8192 + bfrOff[kf]);
            __builtin_amdgcn_s_setprio(1);
            #pragma unroll
            for (int mf = 0; mf < 4; ++mf)
                #pragma unroll
                for (int kf = 0; kf < 4; ++kf)
                    acc[mf][kf] = __builtin_amdgcn_mfma_f32_16x16x32_bf16(
                        af[mf], bfr[kf], acc[mf][kf], 0, 0, 0);
            __builtin_amdgcn_s_setprio(0);

            if (cs == 7) {
                // epilogue: packed (d,k) top-2 update; d = en' - 2*dot
                #pragma unroll
                for (int kf = 0; kf < 4; ++kf) {
                    const u32 kcol = (u32)(kbase + it * 128 + wc * 64 + kf * 16 + ll);
                    #pragma unroll
                    for (int mf = 0; mf < 4; ++mf) {
                        #pragma unroll
                        for (int r = 0; r < 4; ++r) {
                            float d = fmaf(-2.0f, acc[mf][kf][r], en[kf]);
                            float df = __uint_as_float((__float_as_uint(d) & 0xFFFFE000u) | kcol);
                            const int s2 = mf * 4 + r;
                            float t = fmaxf(m1[s2], df);
                            m2[s2] = fminf(m2[s2], t);
                            m1[s2] = fminf(m1[s2], df);
                            acc[mf][kf][r] = 0.0f;
                        }
                    }
                }
            }
            __syncthreads();
        }
    }

    // ---- row-split min via butterfly on a COPY (per-thread m1/m2 preserved!) ----
    float rowm[16];
    #pragma unroll
    for (int s = 0; s < 16; ++s) rowm[s] = m1[s];
    #pragma unroll
    for (int m = 1; m <= 8; m <<= 1)
        #pragma unroll
        for (int s = 0; s < 16; ++s)
            rowm[s] = fminf(rowm[s], __shfl_xor(rowm[s], m, 64));   // packed min over 16 k-lanes

    // LDS reuse (all K-loop barriers passed)
    float* LDSrm = (float*)Bb;             // [128][2]
    float* LDSrmF = (float*)(Bb + 1024);   // [128]
    u32* ccnt = (u32*)(Bb + 1536);
    u32* gbase = (u32*)(Bb + 1540);
    uint2* cbuf = (uint2*)Ab;              // 8192 entries

    if (ll == 0) {
        #pragma unroll
        for (int s = 0; s < 16; ++s) {
            int row_local = wr * 64 + (s >> 2) * 16 + lh * 4 + (s & 3);
            LDSrm[row_local * 2 + wc] = rowm[s];
        }
    }
    if (tid == 0) *ccnt = 0;
    __syncthreads();
    if (tid < 128)
        LDSrmF[tid] = fminf(LDSrm[tid * 2], LDSrm[tid * 2 + 1]);
    __syncthreads();

    // ---- emission (per-thread bests; block-compacted) ----
    #pragma unroll
    for (int s = 0; s < 16; ++s) {
        int row_local = wr * 64 + (s >> 2) * 16 + lh * 4 + (s & 3);
        float rm = __uint_as_float(__float_as_uint(LDSrmF[row_local]) & 0xFFFFE000u);
        float d1 = __uint_as_float(__float_as_uint(m1[s]) & 0xFFFFE000u);
        if (d1 <= rm + MARGIN) {
            u32 pos = atomicAdd(ccnt, 1u);
            uint2 ent = make_uint2((u32)(n0 + row_local), __float_as_uint(m1[s]) & 8191u);
            if (pos < LCAP) cbuf[pos] = ent;
            else { u32 gp = atomicAdd(cnt, 1u); if (gp < CAP) list[gp] = ent; }
        }
        float d2 = __uint_as_float(__float_as_uint(m2[s]) & 0xFFFFE000u);
        if (d2 <= rm + MARGIN) {
            // rare: a 3rd candidate may hide in this thread-slot's 64-k subset -> emit all
            for (int it2 = 0; it2 < 16; ++it2) {
                #pragma unroll
                for (int kf = 0; kf < 4; ++kf) {
                    u32 k = (u32)(kbase + it2 * 128 + wc * 64 + kf * 16 + ll);
                    u32 pos = atomicAdd(ccnt, 1u);
                    uint2 ent = make_uint2((u32)(n0 + row_local), k);
                    if (pos < LCAP) cbuf[pos] = ent;
                    else { u32 gp = atomicAdd(cnt, 1u); if (gp < CAP) list[gp] = ent; }
                }
            }
        }
    }
    __syncthreads();
    if (tid == 0) {
        u32 total = *ccnt; if (total > LCAP) total = LCAP;
        *gbase = atomicAdd(cnt, total);
    }
    __syncthreads();
    u32 total = *ccnt; if (total > LCAP) total = LCAP;
    u32 gb = *gbase;
    for (u32 i = tid; i < total; i += 256) {
        u32 gp = gb + i;
        if (gp < CAP) list[gp] = cbuf[i];
    }
}

// ---------------- exact fp32 recheck of candidates ----------------
__global__ __launch_bounds__(256) void k_exact(const float* __restrict__ zt32,
                                               const float* __restrict__ e,
                                               const float* __restrict__ enorm1,
                                               const u32* __restrict__ cnt,
                                               const uint2* __restrict__ list,
                                               u64* __restrict__ packed) {
    const int nw = gridDim.x * 4;
    const int wid = blockIdx.x * 4 + (threadIdx.x >> 6);
    const int l = threadIdx.x & 63;
    u32 total = *cnt;
    if (total > CAP) total = CAP;
    for (u32 i = wid; i < total; i += nw) {
        uint2 c = list[i];
        const float4 zv = *reinterpret_cast<const float4*>(zt32 + (size_t)c.x * C_DIM + l * 4);
        const float4 ev = *reinterpret_cast<const float4*>(e + (size_t)c.y * C_DIM + l * 4);
        float s = zv.x * ev.x + zv.y * ev.y + zv.z * ev.z + zv.w * ev.w;
        #pragma unroll
        for (int off = 32; off; off >>= 1) s += __shfl_xor(s, off, 64);
        if (l == 0) {
            float d = fmaf(-2.0f, s, enorm1[c.y]);   // +1024 shift uniform: order preserved
            u32 ub = __float_as_uint(d);
            ub = (ub & 0x80000000u) ? ~ub : (ub | 0x80000000u);
            u64 key = ((u64)ub << 32) | (u64)c.y;
            atomicMin(packed + c.x, key);
        }
    }
}

// ---------------- finalize indices (clamped: never fault downstream) ----------------
__global__ __launch_bounds__(256) void k_fin(const u64* __restrict__ packed,
                                             int* __restrict__ fidx,
                                             float* __restrict__ out_idx) {
    int n = blockIdx.x * 256 + threadIdx.x;
    if (n >= N_TOT) return;
    u32 kk = (u32)(packed[n] & 0xFFFFFFFFull);
    if (kk > 8191u) kk = 0u;   // safety net: visible wrong answer instead of GPU fault
    fidx[n] = (int)kk;
    out_idx[n] = (float)kk;
}

// ---------------- gather z_q + loss partials ----------------
#define GBLOCKS 2048
__global__ __launch_bounds__(256) void k_gather(const float* __restrict__ z,
                                                const float* __restrict__ e,
                                                const int* __restrict__ fidx,
                                                float* __restrict__ zq,
                                                float* __restrict__ lpart) {
    float s = 0.0f;
    for (int i = blockIdx.x * 256 + threadIdx.x; i < ZQ_SIZE; i += GBLOCKS * 256) {
        int bb = i >> 18;
        int c = (i >> 10) & 255;
        int hw = i & 1023;
        int n = (bb << 10) | hw;
        float q = e[(size_t)fidx[n] * C_DIM + c];
        float zv = z[i];
        zq[i] = q;
        float d = q - zv;
        s = fmaf(d, d, s);
    }
    #pragma unroll
    for (int off = 32; off; off >>= 1) s += __shfl_xor(s, off, 64);
    __shared__ float wsum[4];
    int lane = threadIdx.x & 63, w = threadIdx.x >> 6;
    if (lane == 0) wsum[w] = s;
    __syncthreads();
    if (threadIdx.x == 0) lpart[blockIdx.x] = wsum[0] + wsum[1] + wsum[2] + wsum[3];
}

__global__ __launch_bounds__(256) void k_loss(const float* __restrict__ lpart,
                                              float* __restrict__ out_loss) {
    float s = 0.0f;
    for (int i = threadIdx.x; i < GBLOCKS; i += 256) s += lpart[i];
    #pragma unroll
    for (int off = 32; off; off >>= 1) s += __shfl_xor(s, off, 64);
    __shared__ float wsum[4];
    int lane = threadIdx.x & 63, w = threadIdx.x >> 6;
    if (lane == 0) wsum[w] = s;
    __syncthreads();
    if (threadIdx.x == 0)
        out_loss[0] = (wsum[0] + wsum[1] + wsum[2] + wsum[3]) * (1.25f / (float)ZQ_SIZE);
}

extern "C" void kernel_launch(void* const* d_in, const int* in_sizes, int n_in,
                              void* d_out, int out_size, void* d_ws, size_t ws_size,
                              hipStream_t stream) {
    const float* z = (const float*)d_in[0];
    const float* e = (const float*)d_in[1];
    float* out = (float*)d_out;
    float* ws = (float*)d_ws;

    float* enorm1 = ws + WS_ENORM;
    u32* cnt = (u32*)(ws + WS_CNT);
    u64* packed = (u64*)(ws + WS_PACKED);
    int* fidx = (int*)(ws + WS_FIDX);
    float* lpart = ws + WS_LPART;
    uint2* list = (uint2*)(ws + WS_LIST);
    float* zt32 = ws + WS_ZT32;
    unsigned short* ztb = (unsigned short*)(ws + WS_ZTB16);
    unsigned short* eb = (unsigned short*)(ws + WS_EB16);

    hipMemsetAsync(cnt, 0, sizeof(u32), stream);
    hipMemsetAsync(packed, 0xFF, (size_t)N_TOT * sizeof(u64), stream);

    k_prep_e<<<dim3(K_DIM / 4), dim3(256), 0, stream>>>(e, eb, enorm1);
    k_prep_z<<<dim3(2048), dim3(256), 0, stream>>>(z, zt32, ztb);
    k_screen<<<dim3(512), dim3(256), 0, stream>>>(ztb, eb, enorm1, cnt, list);
    k_exact<<<dim3(1024), dim3(256), 0, stream>>>(zt32, e, enorm1, cnt, list, packed);
    k_fin<<<dim3(64), dim3(256), 0, stream>>>(packed, fidx, out + IDX_OFF);
    k_gather<<<dim3(GBLOCKS), dim3(256), 0, stream>>>(z, e, fidx, out, lpart);
    k_loss<<<dim3(1), dim3(256), 0, stream>>>(lpart, out + LOSS_OFF);
}